// Round 1
// baseline (2287.547 us; speedup 1.0000x reference)
//
#include <hip/hip_runtime.h>
#include <math.h>

// Problem constants
#define BB 4
#define NN 192
#define DIN 768
#define HD 256
#define G4 1024        // 4*HD
#define HH 512
#define PP 513         // BIAFF+1
#define CLS 10
#define NBIG 5130      // CLS*PP
#define WCO_LD 1051

__device__ __forceinline__ float sigf(float x) { return 1.f / (1.f + expf(-x)); }

// ---------------------------------------------------------------------------
// Generic tiled fp32 GEMM: C[m,n] = act(A[m,:K] . B[n,:K] + bias[n])
// A: M x K (lda), B: N x K row-major, C: M x ldc (pointer may be column-offset)
// M must be a multiple of 64. N,K arbitrary (bounds-checked).
// act: 0 none, 1 exact gelu, 2 leaky_relu(0.01)
// ---------------------------------------------------------------------------
__global__ __launch_bounds__(256)
void gemm_bt(const float* __restrict__ A, const float* __restrict__ B,
             const float* __restrict__ bias, float* __restrict__ C,
             int M, int N, int K, int lda, int ldc, int act)
{
    __shared__ __align__(16) float As[16][68];
    __shared__ __align__(16) float Bs[16][68];
    const int tid = threadIdx.x;
    const int tx = tid & 15, ty = tid >> 4;
    const int m0 = blockIdx.y * 64, n0 = blockIdx.x * 64;
    const int kk = tid & 15, rr = tid >> 4;
    float acc[4][4] = {{0.f}};

    for (int k0 = 0; k0 < K; k0 += 16) {
        const int gk = k0 + kk;
        const bool kin = gk < K;
#pragma unroll
        for (int i = 0; i < 4; ++i) {
            int mm = rr * 4 + i;
            As[kk][mm] = kin ? A[(size_t)(m0 + mm) * lda + gk] : 0.f;
            int nn = n0 + mm;
            Bs[kk][mm] = (kin && nn < N) ? B[(size_t)nn * K + gk] : 0.f;
        }
        __syncthreads();
#pragma unroll
        for (int k = 0; k < 16; ++k) {
            float4 av = *(const float4*)&As[k][ty * 4];
            float4 bv = *(const float4*)&Bs[k][tx * 4];
            float a_[4] = {av.x, av.y, av.z, av.w};
            float b_[4] = {bv.x, bv.y, bv.z, bv.w};
#pragma unroll
            for (int i = 0; i < 4; ++i)
#pragma unroll
                for (int j = 0; j < 4; ++j)
                    acc[i][j] = fmaf(a_[i], b_[j], acc[i][j]);
        }
        __syncthreads();
    }
#pragma unroll
    for (int i = 0; i < 4; ++i) {
        int m = m0 + ty * 4 + i;
#pragma unroll
        for (int j = 0; j < 4; ++j) {
            int n = n0 + tx * 4 + j;
            if (n < N) {
                float v = acc[i][j] + (bias ? bias[n] : 0.f);
                if (act == 1) v = 0.5f * v * (1.f + erff(v * 0.70710678118654752f));
                else if (act == 2) v = v > 0.f ? v : 0.01f * v;
                C[(size_t)m * ldc + n] = v;
            }
        }
    }
}

// ---------------------------------------------------------------------------
// M-GEMM: Mbuf[m, k*513+j] = sum_i h1[m,i] * biaffW[k,i,j]
// B is indexed directly from biaff_W (10,513,513): B[n, i] = biaffW[n/513, i, n%513]
// ---------------------------------------------------------------------------
__global__ __launch_bounds__(256)
void gemm_biaff(const float* __restrict__ A, const float* __restrict__ W,
                float* __restrict__ C)
{
    __shared__ __align__(16) float As[16][68];
    __shared__ __align__(16) float Bs[16][68];
    const int tid = threadIdx.x;
    const int tx = tid & 15, ty = tid >> 4;
    const int m0 = blockIdx.y * 64, n0 = blockIdx.x * 64;
    const int kk = tid & 15, rr = tid >> 4;
    float acc[4][4] = {{0.f}};

    for (int k0 = 0; k0 < PP; k0 += 16) {
        const int gk = k0 + kk;
        const bool kin = gk < PP;
#pragma unroll
        for (int i = 0; i < 4; ++i) {
            int mm = rr * 4 + i;
            As[kk][mm] = kin ? A[(size_t)(m0 + mm) * PP + gk] : 0.f;
            int nn = n0 + mm;
            float bv = 0.f;
            if (kin && nn < NBIG) {
                int kc = nn / PP;
                int j = nn - kc * PP;
                bv = W[((size_t)kc * PP + gk) * PP + j];
            }
            Bs[kk][mm] = bv;
        }
        __syncthreads();
#pragma unroll
        for (int k = 0; k < 16; ++k) {
            float4 av = *(const float4*)&As[k][ty * 4];
            float4 bv = *(const float4*)&Bs[k][tx * 4];
            float a_[4] = {av.x, av.y, av.z, av.w};
            float b_[4] = {bv.x, bv.y, bv.z, bv.w};
#pragma unroll
            for (int i = 0; i < 4; ++i)
#pragma unroll
                for (int j = 0; j < 4; ++j)
                    acc[i][j] = fmaf(a_[i], b_[j], acc[i][j]);
        }
        __syncthreads();
    }
#pragma unroll
    for (int i = 0; i < 4; ++i) {
        int m = m0 + ty * 4 + i;
#pragma unroll
        for (int j = 0; j < 4; ++j) {
            int n = n0 + tx * 4 + j;
            if (n < NBIG) C[(size_t)m * NBIG + n] = acc[i][j];
        }
    }
}

// ---------------------------------------------------------------------------
// Final GEMM + epilogue:
// out[b,k,x,y] = sum_j Mbuf[b*192+x, k*513+j]*t1[b*192+y, j] + hv[b,k,x] + tv[b,k,y] + Tt[k, span]
// rows r = b*1920 + k*192 + x (7680 total), cols y (192)
// ---------------------------------------------------------------------------
__global__ __launch_bounds__(256)
void final_gemm(const float* __restrict__ Mb, const float* __restrict__ t1,
                const float* __restrict__ hv, const float* __restrict__ tv,
                const float* __restrict__ Tt, float* __restrict__ out)
{
    __shared__ __align__(16) float As[16][68];
    __shared__ __align__(16) float Bs[16][68];
    const int tid = threadIdx.x;
    const int tx = tid & 15, ty = tid >> 4;
    const int r0 = blockIdx.y * 64;
    const int b = r0 / 1920;
    const int rem = r0 - b * 1920;
    const int kc = rem / 192;
    const int x0 = rem - kc * 192;
    const int n0 = blockIdx.x * 64;
    const int kk = tid & 15, rr = tid >> 4;
    float acc[4][4] = {{0.f}};

    for (int k0 = 0; k0 < PP; k0 += 16) {
        const int gk = k0 + kk;
        const bool kin = gk < PP;
#pragma unroll
        for (int i = 0; i < 4; ++i) {
            int mm = rr * 4 + i;
            As[kk][mm] = kin ? Mb[(size_t)(b * 192 + x0 + mm) * NBIG + kc * PP + gk] : 0.f;
            Bs[kk][mm] = kin ? t1[(size_t)(b * 192 + n0 + mm) * PP + gk] : 0.f;
        }
        __syncthreads();
#pragma unroll
        for (int k = 0; k < 16; ++k) {
            float4 av = *(const float4*)&As[k][ty * 4];
            float4 bv = *(const float4*)&Bs[k][tx * 4];
            float a_[4] = {av.x, av.y, av.z, av.w};
            float b_[4] = {bv.x, bv.y, bv.z, bv.w};
#pragma unroll
            for (int i = 0; i < 4; ++i)
#pragma unroll
                for (int j = 0; j < 4; ++j)
                    acc[i][j] = fmaf(a_[i], b_[j], acc[i][j]);
        }
        __syncthreads();
    }
    const int bk = b * 10 + kc;
#pragma unroll
    for (int i = 0; i < 4; ++i) {
        int x = x0 + ty * 4 + i;
        float hvv = hv[bk * 192 + x];
#pragma unroll
        for (int j = 0; j < 4; ++j) {
            int y = n0 + tx * 4 + j;
            int d = y - x;
            d = d < -15 ? -15 : (d > 14 ? 14 : d);
            float v = acc[i][j] + hvv + tv[bk * 192 + y] + Tt[kc * 30 + d + 15];
            out[(((size_t)bk) * 192 + x) * 192 + y] = v;
        }
    }
}

// ---------------------------------------------------------------------------
// Whh transpose: Whht[dir, j, g] = Whh_dir[g, j]   (so scan reads coalesced on g)
// ---------------------------------------------------------------------------
__global__ void prep_whht(const float* __restrict__ Wf, const float* __restrict__ Wb,
                          float* __restrict__ Whht)
{
    int idx = blockIdx.x * blockDim.x + threadIdx.x;
    if (idx >= 2 * 256 * 1024) return;
    int dir = idx >> 18;
    int rem = idx & ((1 << 18) - 1);
    int j = rem >> 10;
    int g = rem & 1023;
    const float* W = dir ? Wb : Wf;
    Whht[idx] = W[g * 256 + j];
}

// ---------------------------------------------------------------------------
// BiLSTM scan. One block per (dir, batch). 1024 threads = one gate row each.
// Handles masking by only iterating t < L; wr pre-zeroed. Backward direction
// writes directly to original positions (tt = L-1-t), absorbing the
// take_along_axis reversal.
// ---------------------------------------------------------------------------
__global__ __launch_bounds__(1024)
void lstm_scan(const float* __restrict__ xw, const float* __restrict__ whht,
               const int* __restrict__ wl, float* __restrict__ wr)
{
    const int dir = blockIdx.x >> 2;
    const int b = blockIdx.x & 3;
    const int L = wl[b];
    const int g = threadIdx.x;
    __shared__ float h_s[256];
    __shared__ float gate_s[1024];
    if (g < 256) h_s[g] = 0.f;
    float c = 0.f;
    __syncthreads();
    const float* wp = whht + (size_t)dir * (256 * 1024) + g;
    const float* xcol = xw + dir * 1024 + g;

    for (int t = 0; t < L; ++t) {
        const int tt = (dir == 0) ? t : (L - 1 - t);
        float acc = xcol[(size_t)(b * 192 + tt) * 2048];
#pragma unroll 8
        for (int j = 0; j < 256; ++j)
            acc = fmaf(wp[(size_t)j * 1024], h_s[j], acc);
        gate_s[g] = acc;
        __syncthreads();
        if (g < 256) {
            float iv = sigf(gate_s[g]);
            float fv = sigf(gate_s[256 + g]);
            float gv = tanhf(gate_s[512 + g]);
            float ov = sigf(gate_s[768 + g]);
            c = fv * c + iv * gv;
            float h = ov * tanhf(c);
            h_s[g] = h;
            wr[(size_t)(b * 192 + tt) * 512 + dir * 256 + g] = h;
        }
        __syncthreads();
    }
}

// ---------------------------------------------------------------------------
// h1/t1 packing (append ones column)
// ---------------------------------------------------------------------------
__global__ void pack_h1t1(const float* __restrict__ HT, float* __restrict__ h1,
                          float* __restrict__ t1)
{
    int idx = blockIdx.x * blockDim.x + threadIdx.x;
    if (idx >= 768 * PP) return;
    int m = idx / PP, i = idx - m * PP;
    h1[idx] = (i < 512) ? HT[(size_t)m * 2048 + i] : 1.f;
    t1[idx] = (i < 512) ? HT[(size_t)m * 2048 + 512 + i] : 1.f;
}

// ---------------------------------------------------------------------------
// hv[b,k,x] = head[b,x,:] . Wco[k,:513] ; tv[b,k,y] = tail . Wco[k,513:1026]
// (the trailing "1" element uses Wco[k,512] / Wco[k,1025])
// ---------------------------------------------------------------------------
__global__ __launch_bounds__(192)
void hvtv_kernel(const float* __restrict__ HT, const float* __restrict__ Wco,
                 float* __restrict__ hv, float* __restrict__ tv)
{
    int bk = blockIdx.x;          // 0..39
    int b = bk / 10, k = bk - (bk / 10) * 10;
    int x = threadIdx.x;          // 0..191
    const float* hrow = HT + (size_t)(b * 192 + x) * 2048 + 1024;
    const float* trow = hrow + 512;
    const float* wk = Wco + k * WCO_LD;
    float sh = wk[512], st = wk[1025];
    for (int i = 0; i < 512; ++i) {
        sh = fmaf(hrow[i], wk[i], sh);
        st = fmaf(trow[i], wk[513 + i], st);
    }
    hv[bk * 192 + x] = sh;
    tv[bk * 192 + x] = st;
}

// Tt[k,p] = size_emb[p,:] . Wco[k,1026:1051]
__global__ void ttab_kernel(const float* __restrict__ size_emb,
                            const float* __restrict__ Wco, float* __restrict__ Tt)
{
    int idx = blockIdx.x * blockDim.x + threadIdx.x;
    if (idx >= 300) return;
    int k = idx / 30, p = idx - (idx / 30) * 30;
    float s = 0.f;
    for (int e = 0; e < 25; ++e)
        s = fmaf(size_emb[p * 25 + e], Wco[k * WCO_LD + 1026 + e], s);
    Tt[idx] = s;
}

extern "C" void kernel_launch(void* const* d_in, const int* in_sizes, int n_in,
                              void* d_out, int out_size, void* d_ws, size_t ws_size,
                              hipStream_t stream)
{
    const float* word_reps = (const float*)d_in[0];
    const int*   word_length = (const int*)d_in[1];
    // d_in[2] dist_inputs, d_in[3] loss_mask: dead (conv branch deleted in ref)
    const float* Wih_f = (const float*)d_in[4];
    const float* Whh_f = (const float*)d_in[5];
    const float* b_f   = (const float*)d_in[6];
    const float* Wih_b = (const float*)d_in[7];
    const float* Whh_b = (const float*)d_in[8];
    const float* b_b   = (const float*)d_in[9];
    // 10..19: cln/conv params: dead
    const float* mlp1_w = (const float*)d_in[20];
    const float* mlp1_b = (const float*)d_in[21];
    const float* mlp2_w = (const float*)d_in[22];
    const float* mlp2_b = (const float*)d_in[23];
    const float* head_w = (const float*)d_in[24];
    const float* head_b = (const float*)d_in[25];
    const float* tail_w = (const float*)d_in[26];
    const float* tail_b = (const float*)d_in[27];
    const float* biaffW = (const float*)d_in[28];
    const float* size_emb = (const float*)d_in[29];
    const float* W_co = (const float*)d_in[30];

    float* w = (float*)d_ws;
    float* xw   = w;                 // 768*2048
    float* whht = xw + 768 * 2048;   // 2*256*1024
    float* wr   = whht + 2 * 256 * 1024;   // 768*512
    float* HT   = wr + 768 * 512;    // 768*2048 [gelu1|gelu2|head|tail]
    float* h1   = HT + 768 * 2048;   // 768*513
    float* t1   = h1 + 768 * PP;     // 768*513
    float* Mbuf = t1 + 768 * PP;     // 768*5130
    float* hv   = Mbuf + (size_t)768 * NBIG; // 40*192
    float* tv   = hv + 40 * 192;     // 40*192
    float* Tt   = tv + 40 * 192;     // 300

    // zero wr (positions t >= L must be exactly 0)
    hipMemsetAsync(wr, 0, (size_t)768 * 512 * sizeof(float), stream);

    prep_whht<<<(2 * 256 * 1024 + 255) / 256, 256, 0, stream>>>(Whh_f, Whh_b, whht);

    // xw = word_reps @ [Wih_f; Wih_b]^T + bias   (768 x 2048)
    gemm_bt<<<dim3(16, 12), 256, 0, stream>>>(word_reps, Wih_f, b_f, xw,
                                              768, 1024, 768, 768, 2048, 0);
    gemm_bt<<<dim3(16, 12), 256, 0, stream>>>(word_reps, Wih_b, b_b, xw + 1024,
                                              768, 1024, 768, 768, 2048, 0);

    lstm_scan<<<8, 1024, 0, stream>>>(xw, whht, word_length, wr);

    // HT = [gelu(wr@mlp1^T+b) | gelu(wr@mlp2^T+b) | leaky(wr@head^T+b) | leaky(wr@tail^T+b)]
    gemm_bt<<<dim3(8, 12), 256, 0, stream>>>(wr, mlp1_w, mlp1_b, HT,        768, 512, 512, 512, 2048, 1);
    gemm_bt<<<dim3(8, 12), 256, 0, stream>>>(wr, mlp2_w, mlp2_b, HT + 512,  768, 512, 512, 512, 2048, 1);
    gemm_bt<<<dim3(8, 12), 256, 0, stream>>>(wr, head_w, head_b, HT + 1024, 768, 512, 512, 512, 2048, 2);
    gemm_bt<<<dim3(8, 12), 256, 0, stream>>>(wr, tail_w, tail_b, HT + 1536, 768, 512, 512, 512, 2048, 2);

    pack_h1t1<<<(768 * PP + 255) / 256, 256, 0, stream>>>(HT, h1, t1);
    hvtv_kernel<<<40, 192, 0, stream>>>(HT, W_co, hv, tv);
    ttab_kernel<<<2, 256, 0, stream>>>(size_emb, W_co, Tt);

    // Mbuf[m, k*513+j] = sum_i h1[m,i]*biaffW[k,i,j]
    gemm_biaff<<<dim3(81, 12), 256, 0, stream>>>(h1, biaffW, Mbuf);

    // out = o1^T + o3
    final_gemm<<<dim3(3, 120), 256, 0, stream>>>(Mbuf, t1, hv, tv, Tt, (float*)d_out);
}

// Round 2
// 1266.244 us; speedup vs baseline: 1.8066x; 1.8066x over previous
//
#include <hip/hip_runtime.h>
#include <math.h>

// Problem constants
#define BB 4
#define NN 192
#define DIN 768
#define HD 256
#define G4 1024        // 4*HD
#define HH 512
#define PP 513         // BIAFF+1
#define CLS 10
#define NBIG 5130      // CLS*PP
#define WCO_LD 1051
#define LMAX 192

typedef __attribute__((ext_vector_type(8))) __bf16 bf16x8;
typedef __attribute__((ext_vector_type(4))) float f32x4;

__device__ __forceinline__ float sigf(float x) { return 1.f / (1.f + expf(-x)); }

__device__ __forceinline__ unsigned short f2bf(float f) {
    unsigned int x = __float_as_uint(f);
    unsigned int r = (x + 0x7FFF + ((x >> 16) & 1)) >> 16;
    return (unsigned short)r;
}
__device__ __forceinline__ float bf2f(unsigned short h) {
    return __uint_as_float(((unsigned int)h) << 16);
}

// ---------------------------------------------------------------------------
// Generic tiled fp32 GEMM: C[m,n] = act(A[m,:K] . B[n,:K] + bias[n])
// ---------------------------------------------------------------------------
__global__ __launch_bounds__(256)
void gemm_bt(const float* __restrict__ A, const float* __restrict__ B,
             const float* __restrict__ bias, float* __restrict__ C,
             int M, int N, int K, int lda, int ldc, int act)
{
    __shared__ __align__(16) float As[16][68];
    __shared__ __align__(16) float Bs[16][68];
    const int tid = threadIdx.x;
    const int tx = tid & 15, ty = tid >> 4;
    const int m0 = blockIdx.y * 64, n0 = blockIdx.x * 64;
    const int kk = tid & 15, rr = tid >> 4;
    float acc[4][4] = {{0.f}};

    for (int k0 = 0; k0 < K; k0 += 16) {
        const int gk = k0 + kk;
        const bool kin = gk < K;
#pragma unroll
        for (int i = 0; i < 4; ++i) {
            int mm = rr * 4 + i;
            As[kk][mm] = kin ? A[(size_t)(m0 + mm) * lda + gk] : 0.f;
            int nn = n0 + mm;
            Bs[kk][mm] = (kin && nn < N) ? B[(size_t)nn * K + gk] : 0.f;
        }
        __syncthreads();
#pragma unroll
        for (int k = 0; k < 16; ++k) {
            float4 av = *(const float4*)&As[k][ty * 4];
            float4 bv = *(const float4*)&Bs[k][tx * 4];
            float a_[4] = {av.x, av.y, av.z, av.w};
            float b_[4] = {bv.x, bv.y, bv.z, bv.w};
#pragma unroll
            for (int i = 0; i < 4; ++i)
#pragma unroll
                for (int j = 0; j < 4; ++j)
                    acc[i][j] = fmaf(a_[i], b_[j], acc[i][j]);
        }
        __syncthreads();
    }
#pragma unroll
    for (int i = 0; i < 4; ++i) {
        int m = m0 + ty * 4 + i;
#pragma unroll
        for (int j = 0; j < 4; ++j) {
            int n = n0 + tx * 4 + j;
            if (n < N) {
                float v = acc[i][j] + (bias ? bias[n] : 0.f);
                if (act == 1) v = 0.5f * v * (1.f + erff(v * 0.70710678118654752f));
                else if (act == 2) v = v > 0.f ? v : 0.01f * v;
                C[(size_t)m * ldc + n] = v;
            }
        }
    }
}

// ---------------------------------------------------------------------------
// M-GEMM: Mbuf[m, k*513+j] = sum_i h1[m,i] * biaffW[k,i,j]
// ---------------------------------------------------------------------------
__global__ __launch_bounds__(256)
void gemm_biaff(const float* __restrict__ A, const float* __restrict__ W,
                float* __restrict__ C)
{
    __shared__ __align__(16) float As[16][68];
    __shared__ __align__(16) float Bs[16][68];
    const int tid = threadIdx.x;
    const int tx = tid & 15, ty = tid >> 4;
    const int m0 = blockIdx.y * 64, n0 = blockIdx.x * 64;
    const int kk = tid & 15, rr = tid >> 4;
    float acc[4][4] = {{0.f}};

    for (int k0 = 0; k0 < PP; k0 += 16) {
        const int gk = k0 + kk;
        const bool kin = gk < PP;
#pragma unroll
        for (int i = 0; i < 4; ++i) {
            int mm = rr * 4 + i;
            As[kk][mm] = kin ? A[(size_t)(m0 + mm) * PP + gk] : 0.f;
            int nn = n0 + mm;
            float bv = 0.f;
            if (kin && nn < NBIG) {
                int kc = nn / PP;
                int j = nn - kc * PP;
                bv = W[((size_t)kc * PP + gk) * PP + j];
            }
            Bs[kk][mm] = bv;
        }
        __syncthreads();
#pragma unroll
        for (int k = 0; k < 16; ++k) {
            float4 av = *(const float4*)&As[k][ty * 4];
            float4 bv = *(const float4*)&Bs[k][tx * 4];
            float a_[4] = {av.x, av.y, av.z, av.w};
            float b_[4] = {bv.x, bv.y, bv.z, bv.w};
#pragma unroll
            for (int i = 0; i < 4; ++i)
#pragma unroll
                for (int j = 0; j < 4; ++j)
                    acc[i][j] = fmaf(a_[i], b_[j], acc[i][j]);
        }
        __syncthreads();
    }
#pragma unroll
    for (int i = 0; i < 4; ++i) {
        int m = m0 + ty * 4 + i;
#pragma unroll
        for (int j = 0; j < 4; ++j) {
            int n = n0 + tx * 4 + j;
            if (n < NBIG) C[(size_t)m * NBIG + n] = acc[i][j];
        }
    }
}

// ---------------------------------------------------------------------------
// Final GEMM + epilogue
// ---------------------------------------------------------------------------
__global__ __launch_bounds__(256)
void final_gemm(const float* __restrict__ Mb, const float* __restrict__ t1,
                const float* __restrict__ hv, const float* __restrict__ tv,
                const float* __restrict__ Tt, float* __restrict__ out)
{
    __shared__ __align__(16) float As[16][68];
    __shared__ __align__(16) float Bs[16][68];
    const int tid = threadIdx.x;
    const int tx = tid & 15, ty = tid >> 4;
    const int r0 = blockIdx.y * 64;
    const int b = r0 / 1920;
    const int rem = r0 - b * 1920;
    const int kc = rem / 192;
    const int x0 = rem - kc * 192;
    const int n0 = blockIdx.x * 64;
    const int kk = tid & 15, rr = tid >> 4;
    float acc[4][4] = {{0.f}};

    for (int k0 = 0; k0 < PP; k0 += 16) {
        const int gk = k0 + kk;
        const bool kin = gk < PP;
#pragma unroll
        for (int i = 0; i < 4; ++i) {
            int mm = rr * 4 + i;
            As[kk][mm] = kin ? Mb[(size_t)(b * 192 + x0 + mm) * NBIG + kc * PP + gk] : 0.f;
            Bs[kk][mm] = kin ? t1[(size_t)(b * 192 + n0 + mm) * PP + gk] : 0.f;
        }
        __syncthreads();
#pragma unroll
        for (int k = 0; k < 16; ++k) {
            float4 av = *(const float4*)&As[k][ty * 4];
            float4 bv = *(const float4*)&Bs[k][tx * 4];
            float a_[4] = {av.x, av.y, av.z, av.w};
            float b_[4] = {bv.x, bv.y, bv.z, bv.w};
#pragma unroll
            for (int i = 0; i < 4; ++i)
#pragma unroll
                for (int j = 0; j < 4; ++j)
                    acc[i][j] = fmaf(a_[i], b_[j], acc[i][j]);
        }
        __syncthreads();
    }
    const int bk = b * 10 + kc;
#pragma unroll
    for (int i = 0; i < 4; ++i) {
        int x = x0 + ty * 4 + i;
        float hvv = hv[bk * 192 + x];
#pragma unroll
        for (int j = 0; j < 4; ++j) {
            int y = n0 + tx * 4 + j;
            int d = y - x;
            d = d < -15 ? -15 : (d > 14 ? 14 : d);
            float v = acc[i][j] + hvv + tv[bk * 192 + y] + Tt[kc * 30 + d + 15];
            out[(((size_t)bk) * 192 + x) * 192 + y] = v;
        }
    }
}

// ---------------------------------------------------------------------------
// Pack Whh into per-lane MFMA B-fragments (bf16), gate-interleaved columns.
// Layout: [dh(4)][wave(8)][frag(32)=kt*4+t][lane(64)][e(8)]
// col_glob = half*512 + wave*64 + t*16 + (lane&15); unit=col>>2; gate=col&3
// orig row g = gate*256 + unit; k = kt*32 + (lane>>4)*8 + e
// ---------------------------------------------------------------------------
__global__ void pack_w(const float* __restrict__ Wf, const float* __restrict__ Wb,
                       unsigned short* __restrict__ pw)
{
    int f = blockIdx.x * blockDim.x + threadIdx.x;
    if (f >= 4 * 8 * 32 * 64 * 8) return;
    int e = f & 7;
    int lane = (f >> 3) & 63;
    int frag = (f >> 9) & 31;
    int wave = (f >> 14) & 7;
    int dh = f >> 17;
    int dir = dh >> 1, half = dh & 1;
    int kt = frag >> 2, t = frag & 3;
    int col = half * 512 + wave * 64 + t * 16 + (lane & 15);
    int u = col >> 2, gt = col & 3;
    int g = gt * 256 + u;
    int k = kt * 32 + (lane >> 4) * 8 + e;
    const float* W = dir ? Wb : Wf;
    pw[f] = f2bf(W[g * 256 + k]);
}

// ---------------------------------------------------------------------------
// Weight-stationary MFMA BiLSTM scan.
// 4 blocks: dh = dir*2+half. Each block: 8 waves x 64 cols (512 of 1024 gate
// cols, gate-interleaved). B-frags (bf16) live in VGPRs for all 192 steps.
// A = h (4 batch rows, hi+lo bf16 split). Halves exchange h via agent-scope
// atomics on step-indexed buffers + monotonic flags.
// ---------------------------------------------------------------------------
__global__ __launch_bounds__(512, 2)
void lstm_mfma(const float* __restrict__ xw, const unsigned short* __restrict__ pw,
               const int* __restrict__ wl, float* __restrict__ wr,
               unsigned int* __restrict__ ex, unsigned int* __restrict__ flags)
{
    const int dh = blockIdx.x;            // 0..3
    const int dir = dh >> 1, half = dh & 1;
    const int tid = threadIdx.x;
    const int lane = tid & 63, wid = tid >> 6;

    __shared__ __align__(16) unsigned short h_hi[16 * 256];
    __shared__ __align__(16) unsigned short h_lo[16 * 256];
    __shared__ __align__(16) float gates_s[512 * 4];

    for (int i = tid; i < 16 * 256; i += 512) { h_hi[i] = 0; h_lo[i] = 0; }

    // load stationary B-frags: 32 frags x 16B per lane
    bf16x8 bw[32];
    {
        const unsigned short* base = pw + ((size_t)(dh * 8 + wid) * 32 * 64 + lane) * 8;
#pragma unroll
        for (int i = 0; i < 32; ++i)
            bw[i] = *reinterpret_cast<const bf16x8*>(base + (size_t)i * 64 * 8);
    }

    // update task: thread -> (unit, batch)
    const int u_loc = tid >> 2, bb = tid & 3;
    const int u_glob = half * 128 + u_loc;
    const int Lb = wl[bb];
    float c_state = 0.f, h_state = 0.f;

    // A-frag addressing (bytes), XOR-swizzled rows
    const int row = lane & 15, quad = lane >> 4;
    const int abase = row * 512 + quad * 16;
    const int aswz = (row & 7) << 4;
    const int wswz = bb << 4;   // swizzle for h writes (row=batch, bb<8)

    __syncthreads();

    f32x4 acc[4];
    for (int t = 0; t < LMAX; ++t) {
        // prefetch xw for this step (independent of h)
        int ttok = (dir == 0) ? t : (Lb - 1 - t);
        if (ttok < 0) ttok = 0;
        const float* xrow = xw + ((size_t)(bb * 192 + ttok)) * 2048 + dir * 1024 + u_glob;
        float x0 = xrow[0], x1 = xrow[256], x2 = xrow[512], x3 = xrow[768];

        // ---- MFMA phase: gates_partial = Whh_bf16 . (h_hi + h_lo) ----
#pragma unroll
        for (int tt = 0; tt < 4; ++tt)
#pragma unroll
            for (int e = 0; e < 4; ++e) acc[tt][e] = 0.f;
#pragma unroll
        for (int kt = 0; kt < 8; ++kt) {
            int off = (abase + kt * 64) ^ aswz;
            bf16x8 ah = *reinterpret_cast<const bf16x8*>((const char*)h_hi + off);
            bf16x8 al = *reinterpret_cast<const bf16x8*>((const char*)h_lo + off);
#pragma unroll
            for (int tt = 0; tt < 4; ++tt) {
                acc[tt] = __builtin_amdgcn_mfma_f32_16x16x32_bf16(ah, bw[kt * 4 + tt], acc[tt], 0, 0, 0);
                acc[tt] = __builtin_amdgcn_mfma_f32_16x16x32_bf16(al, bw[kt * 4 + tt], acc[tt], 0, 0, 0);
            }
        }
        if (lane < 16) {   // rows 0-3 (batches) live in lanes 0-15, regs 0-3
#pragma unroll
            for (int tt = 0; tt < 4; ++tt) {
                int col_loc = wid * 64 + tt * 16 + lane;
                *reinterpret_cast<f32x4*>(&gates_s[col_loc * 4]) = acc[tt];
            }
        }
        __syncthreads();

        // ---- update phase: one (unit, batch) per thread ----
        float gi = gates_s[(u_loc * 4 + 0) * 4 + bb] + x0;
        float gf = gates_s[(u_loc * 4 + 1) * 4 + bb] + x1;
        float gg = gates_s[(u_loc * 4 + 2) * 4 + bb] + x2;
        float go = gates_s[(u_loc * 4 + 3) * 4 + bb] + x3;
        float cn = sigf(gf) * c_state + sigf(gi) * tanhf(gg);
        float hn = sigf(go) * tanhf(cn);
        if (t < Lb) {
            c_state = cn; h_state = hn;
            wr[((size_t)(bb * 192 + ttok)) * 512 + dir * 256 + u_glob] = hn;
        }
        unsigned short hi_b = f2bf(h_state);
        unsigned short lo_b = f2bf(h_state - bf2f(hi_b));
        {
            int lb = (bb * 512 + u_glob * 2) ^ wswz;
            *(unsigned short*)((char*)h_hi + lb) = hi_b;
            *(unsigned short*)((char*)h_lo + lb) = lo_b;
        }
        unsigned int packv = ((unsigned int)lo_b << 16) | hi_b;
        __hip_atomic_store(&ex[((size_t)dh * LMAX + t) * 512 + tid], packv,
                           __ATOMIC_RELAXED, __HIP_MEMORY_SCOPE_AGENT);
        __syncthreads();

        // ---- cross-half handshake ----
        if (tid == 0) {
            __threadfence();
            __hip_atomic_store(&flags[dh], (unsigned int)(t + 1),
                               __ATOMIC_RELEASE, __HIP_MEMORY_SCOPE_AGENT);
            while (__hip_atomic_load(&flags[dh ^ 1], __ATOMIC_ACQUIRE,
                                     __HIP_MEMORY_SCOPE_AGENT) < (unsigned int)(t + 1)) {
                __builtin_amdgcn_s_sleep(1);
            }
        }
        __syncthreads();

        // ---- import partner h ----
        {
            unsigned int pv = __hip_atomic_load(&ex[((size_t)(dh ^ 1) * LMAX + t) * 512 + tid],
                                                __ATOMIC_RELAXED, __HIP_MEMORY_SCOPE_AGENT);
            int pu = (half ^ 1) * 128 + (tid >> 2);
            int lb = (bb * 512 + pu * 2) ^ wswz;
            *(unsigned short*)((char*)h_hi + lb) = (unsigned short)(pv & 0xFFFFu);
            *(unsigned short*)((char*)h_lo + lb) = (unsigned short)(pv >> 16);
        }
        __syncthreads();
    }
}

// ---------------------------------------------------------------------------
// h1/t1 packing (append ones column)
// ---------------------------------------------------------------------------
__global__ void pack_h1t1(const float* __restrict__ HT, float* __restrict__ h1,
                          float* __restrict__ t1)
{
    int idx = blockIdx.x * blockDim.x + threadIdx.x;
    if (idx >= 768 * PP) return;
    int m = idx / PP, i = idx - m * PP;
    h1[idx] = (i < 512) ? HT[(size_t)m * 2048 + i] : 1.f;
    t1[idx] = (i < 512) ? HT[(size_t)m * 2048 + 512 + i] : 1.f;
}

__global__ __launch_bounds__(192)
void hvtv_kernel(const float* __restrict__ HT, const float* __restrict__ Wco,
                 float* __restrict__ hv, float* __restrict__ tv)
{
    int bk = blockIdx.x;
    int b = bk / 10, k = bk - (bk / 10) * 10;
    int x = threadIdx.x;
    const float* hrow = HT + (size_t)(b * 192 + x) * 2048 + 1024;
    const float* trow = hrow + 512;
    const float* wk = Wco + k * WCO_LD;
    float sh = wk[512], st = wk[1025];
    for (int i = 0; i < 512; ++i) {
        sh = fmaf(hrow[i], wk[i], sh);
        st = fmaf(trow[i], wk[513 + i], st);
    }
    hv[bk * 192 + x] = sh;
    tv[bk * 192 + x] = st;
}

__global__ void ttab_kernel(const float* __restrict__ size_emb,
                            const float* __restrict__ Wco, float* __restrict__ Tt)
{
    int idx = blockIdx.x * blockDim.x + threadIdx.x;
    if (idx >= 300) return;
    int k = idx / 30, p = idx - (idx / 30) * 30;
    float s = 0.f;
    for (int e = 0; e < 25; ++e)
        s = fmaf(size_emb[p * 25 + e], Wco[k * WCO_LD + 1026 + e], s);
    Tt[idx] = s;
}

extern "C" void kernel_launch(void* const* d_in, const int* in_sizes, int n_in,
                              void* d_out, int out_size, void* d_ws, size_t ws_size,
                              hipStream_t stream)
{
    const float* word_reps = (const float*)d_in[0];
    const int*   word_length = (const int*)d_in[1];
    const float* Wih_f = (const float*)d_in[4];
    const float* Whh_f = (const float*)d_in[5];
    const float* b_f   = (const float*)d_in[6];
    const float* Wih_b = (const float*)d_in[7];
    const float* Whh_b = (const float*)d_in[8];
    const float* b_b   = (const float*)d_in[9];
    const float* mlp1_w = (const float*)d_in[20];
    const float* mlp1_b = (const float*)d_in[21];
    const float* mlp2_w = (const float*)d_in[22];
    const float* mlp2_b = (const float*)d_in[23];
    const float* head_w = (const float*)d_in[24];
    const float* head_b = (const float*)d_in[25];
    const float* tail_w = (const float*)d_in[26];
    const float* tail_b = (const float*)d_in[27];
    const float* biaffW = (const float*)d_in[28];
    const float* size_emb = (const float*)d_in[29];
    const float* W_co = (const float*)d_in[30];

    float* w = (float*)d_ws;
    float* xw   = w;                              // 768*2048
    float* pw_f = xw + 768 * 2048;                // 524288 ushort = 262144 floats
    unsigned short* pw = (unsigned short*)pw_f;
    float* wr   = pw_f + 262144;                  // 768*512
    float* HT   = wr + 768 * 512;                 // 768*2048
    float* h1   = HT + 768 * 2048;                // 768*513
    float* t1   = h1 + 768 * PP;                  // 768*513
    float* Mbuf = t1 + 768 * PP;                  // 768*5130
    float* hv   = Mbuf + (size_t)768 * NBIG;      // 40*192
    float* tv   = hv + 40 * 192;
    float* Tt   = tv + 40 * 192;                  // 300
    unsigned int* ex = (unsigned int*)(Tt + 300); // 4*192*512
    unsigned int* flags = ex + 4 * LMAX * 512;    // 4

    hipMemsetAsync(wr, 0, (size_t)768 * 512 * sizeof(float), stream);
    hipMemsetAsync(flags, 0, 4 * sizeof(unsigned int), stream);

    pack_w<<<(4 * 8 * 32 * 64 * 8 + 255) / 256, 256, 0, stream>>>(Whh_f, Whh_b, pw);

    // xw = word_reps @ [Wih_f; Wih_b]^T + bias   (768 x 2048, fp32 exact)
    gemm_bt<<<dim3(16, 12), 256, 0, stream>>>(word_reps, Wih_f, b_f, xw,
                                              768, 1024, 768, 768, 2048, 0);
    gemm_bt<<<dim3(16, 12), 256, 0, stream>>>(word_reps, Wih_b, b_b, xw + 1024,
                                              768, 1024, 768, 768, 2048, 0);

    lstm_mfma<<<4, 512, 0, stream>>>(xw, pw, word_length, wr, ex, flags);

    gemm_bt<<<dim3(8, 12), 256, 0, stream>>>(wr, mlp1_w, mlp1_b, HT,        768, 512, 512, 512, 2048, 1);
    gemm_bt<<<dim3(8, 12), 256, 0, stream>>>(wr, mlp2_w, mlp2_b, HT + 512,  768, 512, 512, 512, 2048, 1);
    gemm_bt<<<dim3(8, 12), 256, 0, stream>>>(wr, head_w, head_b, HT + 1024, 768, 512, 512, 512, 2048, 2);
    gemm_bt<<<dim3(8, 12), 256, 0, stream>>>(wr, tail_w, tail_b, HT + 1536, 768, 512, 512, 512, 2048, 2);

    pack_h1t1<<<(768 * PP + 255) / 256, 256, 0, stream>>>(HT, h1, t1);
    hvtv_kernel<<<40, 192, 0, stream>>>(HT, W_co, hv, tv);
    ttab_kernel<<<2, 256, 0, stream>>>(size_emb, W_co, Tt);

    gemm_biaff<<<dim3(81, 12), 256, 0, stream>>>(h1, biaffW, Mbuf);

    final_gemm<<<dim3(3, 120), 256, 0, stream>>>(Mbuf, t1, hv, tv, Tt, (float*)d_out);
}

// Round 3
// 826.010 us; speedup vs baseline: 2.7694x; 1.5330x over previous
//
#include <hip/hip_runtime.h>
#include <math.h>

// Problem constants
#define BB 4
#define NN 192
#define DIN 768
#define HD 256
#define HH 512
#define PP 513         // BIAFF+1
#define CLS 10
#define NBIG 5130      // CLS*PP
#define KP 544         // PP padded to 17*32
#define WCO_LD 1051
#define LMAX 192

typedef __attribute__((ext_vector_type(8))) __bf16 bf16x8;
typedef __attribute__((ext_vector_type(4))) float f32x4;
typedef unsigned short u16;
typedef unsigned long long u64;

__device__ __forceinline__ float sigf(float x) { return 1.f / (1.f + expf(-x)); }

__device__ __forceinline__ u16 f2bf(float f) {
    unsigned int x = __float_as_uint(f);
    unsigned int r = (x + 0x7FFF + ((x >> 16) & 1)) >> 16;
    return (u16)r;
}
__device__ __forceinline__ float bf2f(u16 h) {
    return __uint_as_float(((unsigned int)h) << 16);
}

// ---------------------------------------------------------------------------
// Generic fp32 -> (hi, lo) bf16 split
// ---------------------------------------------------------------------------
__global__ void split_hl(const float* __restrict__ src, u16* __restrict__ hi,
                         u16* __restrict__ lo, int n)
{
    int i = blockIdx.x * blockDim.x + threadIdx.x;
    if (i >= n) return;
    float v = src[i];
    u16 h = f2bf(v);
    hi[i] = h;
    lo[i] = f2bf(v - bf2f(h));
}

// ---------------------------------------------------------------------------
// HT -> h1/t1 hi/lo splits with ones column and zero padding to KP=544
// ---------------------------------------------------------------------------
__global__ void split_ht(const float* __restrict__ HT, u16* __restrict__ h1h,
                         u16* __restrict__ h1l, u16* __restrict__ t1h,
                         u16* __restrict__ t1l)
{
    int idx = blockIdx.x * blockDim.x + threadIdx.x;
    if (idx >= 768 * KP) return;
    int m = idx / KP, k = idx - m * KP;
    float hv = (k < 512) ? HT[(size_t)m * 2048 + k] : (k == 512 ? 1.f : 0.f);
    float tv = (k < 512) ? HT[(size_t)m * 2048 + 512 + k] : (k == 512 ? 1.f : 0.f);
    u16 hh = f2bf(hv);
    h1h[idx] = hh; h1l[idx] = f2bf(hv - bf2f(hh));
    u16 th = f2bf(tv);
    t1h[idx] = th; t1l[idx] = f2bf(tv - bf2f(th));
}

// ---------------------------------------------------------------------------
// biaffW (10,513,513) -> Wsp[n=kc*513+j][k] hi/lo bf16, K padded to 544 (zeros)
// Tiled 32x32 transpose through LDS so both sides stay coalesced.
// ---------------------------------------------------------------------------
__global__ void wsplit_kernel(const float* __restrict__ W, u16* __restrict__ Wh,
                              u16* __restrict__ Wl)
{
    __shared__ float tile[32][33];
    int kc = blockIdx.z, k0 = blockIdx.x * 32, j0 = blockIdx.y * 32;
    int tx = threadIdx.x, ty = threadIdx.y;   // 32 x 8
#pragma unroll
    for (int yy = 0; yy < 32; yy += 8) {
        int k = k0 + ty + yy, j = j0 + tx;
        tile[ty + yy][tx] = (k < 513 && j < 513) ? W[((size_t)kc * 513 + k) * 513 + j] : 0.f;
    }
    __syncthreads();
#pragma unroll
    for (int yy = 0; yy < 32; yy += 8) {
        int j = j0 + ty + yy, k = k0 + tx;
        if (j < 513 && k < KP) {
            float v = tile[tx][ty + yy];
            size_t o = ((size_t)kc * 513 + j) * KP + k;
            u16 h = f2bf(v);
            Wh[o] = h; Wl[o] = f2bf(v - bf2f(h));
        }
    }
}

// ---------------------------------------------------------------------------
// Generic hi/lo bf16 MFMA GEMM: C[m,n] = act(A[m,:K].B[n,:K] + bias[n])
// M = gridDim.y*64 (full), N = gridDim.x*64, K % 32 == 0. LDS-free.
// act: 0 none, 1 exact gelu, 2 leaky_relu(0.01)
// ---------------------------------------------------------------------------
__global__ __launch_bounds__(256)
void gemm_mfma_hl(const u16* __restrict__ Ah, const u16* __restrict__ Al,
                  const u16* __restrict__ Bh, const u16* __restrict__ Bl,
                  const float* __restrict__ bias, float* __restrict__ C,
                  int K, int ldc, int act)
{
    const int lane = threadIdx.x & 63, w = threadIdx.x >> 6;
    const int m0 = blockIdx.y * 64;
    const int n0 = blockIdx.x * 64 + w * 16;
    const int arow = m0 + (lane & 15);
    const int brow = n0 + (lane & 15);
    const int koff = (lane >> 4) * 8;
    f32x4 acc[4] = {};

    for (int k0 = 0; k0 < K; k0 += 32) {
        bf16x8 bh = *(const bf16x8*)(Bh + (size_t)brow * K + k0 + koff);
        bf16x8 bl = *(const bf16x8*)(Bl + (size_t)brow * K + k0 + koff);
#pragma unroll
        for (int mi = 0; mi < 4; ++mi) {
            size_t ao = (size_t)(arow + mi * 16) * K + k0 + koff;
            bf16x8 ah = *(const bf16x8*)(Ah + ao);
            bf16x8 al = *(const bf16x8*)(Al + ao);
            acc[mi] = __builtin_amdgcn_mfma_f32_16x16x32_bf16(ah, bh, acc[mi], 0, 0, 0);
            acc[mi] = __builtin_amdgcn_mfma_f32_16x16x32_bf16(ah, bl, acc[mi], 0, 0, 0);
            acc[mi] = __builtin_amdgcn_mfma_f32_16x16x32_bf16(al, bh, acc[mi], 0, 0, 0);
        }
    }
    const float bv = bias ? bias[n0 + (lane & 15)] : 0.f;
    const int cn = n0 + (lane & 15);
#pragma unroll
    for (int mi = 0; mi < 4; ++mi)
#pragma unroll
        for (int r = 0; r < 4; ++r) {
            int m = m0 + mi * 16 + (lane >> 4) * 4 + r;
            float v = acc[mi][r] + bv;
            if (act == 1) v = 0.5f * v * (1.f + erff(v * 0.70710678118654752f));
            else if (act == 2) v = v > 0.f ? v : 0.01f * v;
            C[(size_t)m * ldc + cn] = v;
        }
}

// ---------------------------------------------------------------------------
// Biaffine M-GEMM (MFMA hi/lo): Mb[m][kc*544+j] = sum_i h1[m,i]*W[kc,i,j]
// Output written directly as hi/lo bf16 pair (pads pre-zeroed by memset).
// ---------------------------------------------------------------------------
__global__ __launch_bounds__(256)
void biaff_mfma(const u16* __restrict__ Ah, const u16* __restrict__ Al,
                const u16* __restrict__ Wh, const u16* __restrict__ Wl,
                u16* __restrict__ Mh, u16* __restrict__ Ml)
{
    const int lane = threadIdx.x & 63, w = threadIdx.x >> 6;
    const int m0 = blockIdx.y * 64;
    const int n0 = blockIdx.x * 128 + w * 32;
    const int arow = m0 + (lane & 15);
    const int koff = (lane >> 4) * 8;
    f32x4 acc[4][2] = {};

    for (int c = 0; c < 17; ++c) {
        const int k0 = c * 32 + koff;
        bf16x8 bh[2], bl[2];
#pragma unroll
        for (int ni = 0; ni < 2; ++ni) {
            size_t bo = (size_t)(n0 + ni * 16 + (lane & 15)) * KP + k0;
            bh[ni] = *(const bf16x8*)(Wh + bo);
            bl[ni] = *(const bf16x8*)(Wl + bo);
        }
#pragma unroll
        for (int mi = 0; mi < 4; ++mi) {
            size_t ao = (size_t)(arow + mi * 16) * KP + k0;
            bf16x8 ah = *(const bf16x8*)(Ah + ao);
            bf16x8 al = *(const bf16x8*)(Al + ao);
#pragma unroll
            for (int ni = 0; ni < 2; ++ni) {
                acc[mi][ni] = __builtin_amdgcn_mfma_f32_16x16x32_bf16(ah, bh[ni], acc[mi][ni], 0, 0, 0);
                acc[mi][ni] = __builtin_amdgcn_mfma_f32_16x16x32_bf16(ah, bl[ni], acc[mi][ni], 0, 0, 0);
                acc[mi][ni] = __builtin_amdgcn_mfma_f32_16x16x32_bf16(al, bh[ni], acc[mi][ni], 0, 0, 0);
            }
        }
    }
#pragma unroll
    for (int mi = 0; mi < 4; ++mi)
#pragma unroll
        for (int ni = 0; ni < 2; ++ni) {
            int n = n0 + ni * 16 + (lane & 15);
            if (n < NBIG) {
                int kc = n / PP, j = n - kc * PP;
#pragma unroll
                for (int r = 0; r < 4; ++r) {
                    int m = m0 + mi * 16 + (lane >> 4) * 4 + r;
                    float v = acc[mi][ni][r];
                    u16 h = f2bf(v);
                    size_t o = (size_t)m * (CLS * KP) + kc * KP + j;
                    Mh[o] = h; Ml[o] = f2bf(v - bf2f(h));
                }
            }
        }
}

// ---------------------------------------------------------------------------
// Final GEMM (MFMA hi/lo) + epilogue:
// out[bk,x,y] = sum_j Mb[b*192+x][kc*544+j]*t1[b*192+y][j] + hv + tv + Tt
// ---------------------------------------------------------------------------
__global__ __launch_bounds__(256)
void final_mfma(const u16* __restrict__ Mh, const u16* __restrict__ Ml,
                const u16* __restrict__ Th, const u16* __restrict__ Tl,
                const float* __restrict__ hv, const float* __restrict__ tv,
                const float* __restrict__ Tt, float* __restrict__ out)
{
    const int lane = threadIdx.x & 63, w = threadIdx.x >> 6;
    const int r0 = blockIdx.y * 64;
    const int b = r0 / 1920;
    const int rem = r0 - b * 1920;
    const int kc = rem / 192;
    const int x0 = rem - kc * 192;
    const int n0 = blockIdx.x * 64 + w * 16;
    const int koff = (lane >> 4) * 8;
    const size_t abase = (size_t)(b * 192 + x0 + (lane & 15)) * (CLS * KP) + kc * KP;
    const size_t bbase = (size_t)(b * 192 + n0 + (lane & 15)) * KP;
    f32x4 acc[4] = {};

    for (int c = 0; c < 17; ++c) {
        const int k0 = c * 32 + koff;
        bf16x8 bh = *(const bf16x8*)(Th + bbase + k0);
        bf16x8 bl = *(const bf16x8*)(Tl + bbase + k0);
#pragma unroll
        for (int mi = 0; mi < 4; ++mi) {
            size_t ao = abase + (size_t)mi * 16 * (CLS * KP) + k0;
            bf16x8 ah = *(const bf16x8*)(Mh + ao);
            bf16x8 al = *(const bf16x8*)(Ml + ao);
            acc[mi] = __builtin_amdgcn_mfma_f32_16x16x32_bf16(ah, bh, acc[mi], 0, 0, 0);
            acc[mi] = __builtin_amdgcn_mfma_f32_16x16x32_bf16(ah, bl, acc[mi], 0, 0, 0);
            acc[mi] = __builtin_amdgcn_mfma_f32_16x16x32_bf16(al, bh, acc[mi], 0, 0, 0);
        }
    }
    const int bk = b * 10 + kc;
    const int y = n0 + (lane & 15);
    const float tvv = tv[bk * 192 + y];
#pragma unroll
    for (int mi = 0; mi < 4; ++mi)
#pragma unroll
        for (int r = 0; r < 4; ++r) {
            int x = x0 + mi * 16 + (lane >> 4) * 4 + r;
            int d = y - x;
            d = d < -15 ? -15 : (d > 14 ? 14 : d);
            float v = acc[mi][r] + hv[bk * 192 + x] + tvv + Tt[kc * 30 + d + 15];
            out[(size_t)(bk * 192 + x) * 192 + y] = v;
        }
}

// ---------------------------------------------------------------------------
// Pack Whh into per-lane MFMA B-fragments (bf16), gate-interleaved columns.
// ---------------------------------------------------------------------------
__global__ void pack_w(const float* __restrict__ Wf, const float* __restrict__ Wb,
                       u16* __restrict__ pw)
{
    int f = blockIdx.x * blockDim.x + threadIdx.x;
    if (f >= 4 * 8 * 32 * 64 * 8) return;
    int e = f & 7;
    int lane = (f >> 3) & 63;
    int frag = (f >> 9) & 31;
    int wave = (f >> 14) & 7;
    int dh = f >> 17;
    int dir = dh >> 1, half = dh & 1;
    int kt = frag >> 2, t = frag & 3;
    int col = half * 512 + wave * 64 + t * 16 + (lane & 15);
    int u = col >> 2, gt = col & 3;
    int g = gt * 256 + u;
    int k = kt * 32 + (lane >> 4) * 8 + e;
    const float* W = dir ? Wb : Wf;
    pw[f] = f2bf(W[g * 256 + k]);
}

// ---------------------------------------------------------------------------
// Weight-stationary MFMA BiLSTM scan with single-word stamped exchange.
// 4 blocks: dh = dir*2+half. Exchange: each thread stores {pack,stamp} as one
// 64b relaxed atomic into slot (dh, t&1, tid) and polls the symmetric partner
// word. The post-import __syncthreads provides the 2-deep buffer invariant.
// ---------------------------------------------------------------------------
__global__ __launch_bounds__(512, 2)
void lstm_mfma(const float* __restrict__ xw, const u16* __restrict__ pw,
               const int* __restrict__ wl, float* __restrict__ wr,
               u64* __restrict__ ex)
{
    const int dh = blockIdx.x;            // 0..3
    const int dir = dh >> 1, half = dh & 1;
    const int tid = threadIdx.x;
    const int lane = tid & 63, wid = tid >> 6;

    __shared__ __align__(16) u16 h_hi[16 * 256];
    __shared__ __align__(16) u16 h_lo[16 * 256];
    __shared__ __align__(16) float gates_s[512 * 4];

    for (int i = tid; i < 16 * 256; i += 512) { h_hi[i] = 0; h_lo[i] = 0; }

    // stationary B-frags: 32 x 16B per lane
    bf16x8 bw[32];
    {
        const u16* base = pw + ((size_t)(dh * 8 + wid) * 32 * 64 + lane) * 8;
#pragma unroll
        for (int i = 0; i < 32; ++i)
            bw[i] = *reinterpret_cast<const bf16x8*>(base + (size_t)i * 64 * 8);
    }

    const int u_loc = tid >> 2, bb = tid & 3;
    const int u_glob = half * 128 + u_loc;
    const int Lb = wl[bb];
    float c_state = 0.f, h_state = 0.f;

    const int row = lane & 15, quad = lane >> 4;
    const int abase = row * 512 + quad * 16;
    const int aswz = (row & 7) << 4;
    const int wswz = bb << 4;

    __syncthreads();

    f32x4 acc[4];
    for (int t = 0; t < LMAX; ++t) {
        int ttok = (dir == 0) ? t : (Lb - 1 - t);
        if (ttok < 0) ttok = 0;
        const float* xrow = xw + ((size_t)(bb * 192 + ttok)) * 2048 + dir * 1024 + u_glob;
        float x0 = xrow[0], x1 = xrow[256], x2 = xrow[512], x3 = xrow[768];

        // ---- MFMA phase ----
#pragma unroll
        for (int tt = 0; tt < 4; ++tt)
#pragma unroll
            for (int e = 0; e < 4; ++e) acc[tt][e] = 0.f;
#pragma unroll
        for (int kt = 0; kt < 8; ++kt) {
            int off = (abase + kt * 64) ^ aswz;
            bf16x8 ah = *reinterpret_cast<const bf16x8*>((const char*)h_hi + off);
            bf16x8 al = *reinterpret_cast<const bf16x8*>((const char*)h_lo + off);
#pragma unroll
            for (int tt = 0; tt < 4; ++tt) {
                acc[tt] = __builtin_amdgcn_mfma_f32_16x16x32_bf16(ah, bw[kt * 4 + tt], acc[tt], 0, 0, 0);
                acc[tt] = __builtin_amdgcn_mfma_f32_16x16x32_bf16(al, bw[kt * 4 + tt], acc[tt], 0, 0, 0);
            }
        }
        if (lane < 16) {
#pragma unroll
            for (int tt = 0; tt < 4; ++tt) {
                int col_loc = wid * 64 + tt * 16 + lane;
                *reinterpret_cast<f32x4*>(&gates_s[col_loc * 4]) = acc[tt];
            }
        }
        __syncthreads();

        // ---- update phase: one (unit, batch) per thread ----
        float gi = gates_s[(u_loc * 4 + 0) * 4 + bb] + x0;
        float gf = gates_s[(u_loc * 4 + 1) * 4 + bb] + x1;
        float gg = gates_s[(u_loc * 4 + 2) * 4 + bb] + x2;
        float go = gates_s[(u_loc * 4 + 3) * 4 + bb] + x3;
        float cn = sigf(gf) * c_state + sigf(gi) * tanhf(gg);
        float hn = sigf(go) * tanhf(cn);
        if (t < Lb) {
            c_state = cn; h_state = hn;
            wr[((size_t)(bb * 192 + ttok)) * 512 + dir * 256 + u_glob] = hn;
        }
        u16 hi_b = f2bf(h_state);
        u16 lo_b = f2bf(h_state - bf2f(hi_b));
        {
            int lb = (bb * 512 + u_glob * 2) ^ wswz;
            *(u16*)((char*)h_hi + lb) = hi_b;
            *(u16*)((char*)h_lo + lb) = lo_b;
        }
        unsigned int packv = ((unsigned int)lo_b << 16) | hi_b;

        // ---- stamped 64b exchange ----
        u64 vv = (u64)packv | ((u64)(unsigned int)(t + 1) << 32);
        __hip_atomic_store(&ex[((size_t)dh * 2 + (t & 1)) * 512 + tid], vv,
                           __ATOMIC_RELAXED, __HIP_MEMORY_SCOPE_AGENT);
        u64 pv;
        do {
            pv = __hip_atomic_load(&ex[((size_t)(dh ^ 1) * 2 + (t & 1)) * 512 + tid],
                                   __ATOMIC_RELAXED, __HIP_MEMORY_SCOPE_AGENT);
            if ((unsigned int)(pv >> 32) == (unsigned int)(t + 1)) break;
            __builtin_amdgcn_s_sleep(1);
        } while (true);
        {
            unsigned int pk = (unsigned int)pv;
            int pu = (half ^ 1) * 128 + (tid >> 2);
            int lb = (bb * 512 + pu * 2) ^ wswz;
            *(u16*)((char*)h_hi + lb) = (u16)(pk & 0xFFFFu);
            *(u16*)((char*)h_lo + lb) = (u16)(pk >> 16);
        }
        __syncthreads();
    }
}

// ---------------------------------------------------------------------------
// hv/tv and Tt epilogue tables
// ---------------------------------------------------------------------------
__global__ __launch_bounds__(192)
void hvtv_kernel(const float* __restrict__ HT, const float* __restrict__ Wco,
                 float* __restrict__ hv, float* __restrict__ tv)
{
    int bk = blockIdx.x;
    int b = bk / 10, k = bk - (bk / 10) * 10;
    int x = threadIdx.x;
    const float* hrow = HT + (size_t)(b * 192 + x) * 2048 + 1024;
    const float* trow = hrow + 512;
    const float* wk = Wco + k * WCO_LD;
    float sh = wk[512], st = wk[1025];
    for (int i = 0; i < 512; ++i) {
        sh = fmaf(hrow[i], wk[i], sh);
        st = fmaf(trow[i], wk[513 + i], st);
    }
    hv[bk * 192 + x] = sh;
    tv[bk * 192 + x] = st;
}

__global__ void ttab_kernel(const float* __restrict__ size_emb,
                            const float* __restrict__ Wco, float* __restrict__ Tt)
{
    int idx = blockIdx.x * blockDim.x + threadIdx.x;
    if (idx >= 300) return;
    int k = idx / 30, p = idx - (idx / 30) * 30;
    float s = 0.f;
    for (int e = 0; e < 25; ++e)
        s = fmaf(size_emb[p * 25 + e], Wco[k * WCO_LD + 1026 + e], s);
    Tt[idx] = s;
}

extern "C" void kernel_launch(void* const* d_in, const int* in_sizes, int n_in,
                              void* d_out, int out_size, void* d_ws, size_t ws_size,
                              hipStream_t stream)
{
    const float* word_reps = (const float*)d_in[0];
    const int*   word_length = (const int*)d_in[1];
    const float* Wih_f = (const float*)d_in[4];
    const float* Whh_f = (const float*)d_in[5];
    const float* b_f   = (const float*)d_in[6];
    const float* Wih_b = (const float*)d_in[7];
    const float* Whh_b = (const float*)d_in[8];
    const float* b_b   = (const float*)d_in[9];
    const float* mlp1_w = (const float*)d_in[20];
    const float* mlp1_b = (const float*)d_in[21];
    const float* mlp2_w = (const float*)d_in[22];
    const float* mlp2_b = (const float*)d_in[23];
    const float* head_w = (const float*)d_in[24];
    const float* head_b = (const float*)d_in[25];
    const float* tail_w = (const float*)d_in[26];
    const float* tail_b = (const float*)d_in[27];
    const float* biaffW = (const float*)d_in[28];
    const float* size_emb = (const float*)d_in[29];
    const float* W_co = (const float*)d_in[30];

    float* W = (float*)d_ws;
    // ---- region A (reused by Mb_hi after the mid GEMMs are done) ----
    float* xw   = W;                              // 1,572,864 f32
    u16*   pw   = (u16*)(W + 1572864);            // 524,288 u16 = 262,144 f32
    float* wr   = W + 1835008;                    // 393,216 f32   (region A end 2,228,224)
    u16*   Mbh  = (u16*)W;                        // 4,177,920 u16 = 8,355,840 B <= 8,912,896 B
    // ---- stable region ----
    float* HT   = W + 2228224;                    // 1,572,864
    u16* h1h = (u16*)(W + 3801088);               // 417,792 u16 each
    u16* h1l = (u16*)(W + 4009984);
    u16* t1h = (u16*)(W + 4218880);
    u16* t1l = (u16*)(W + 4427776);
    u16* Wsph = (u16*)(W + 4636672);              // 5248*544 = 2,854,912 u16
    u16* Wspl = (u16*)(W + 6064128);
    u16* Mbl  = (u16*)(W + 7491584);              // 4,177,920 u16
    float* hv = W + 9580544;                      // 7,680
    float* tv = W + 9588224;                      // 7,680
    float* Tt = W + 9595904;                      // 304
    u64* ex   = (u64*)(W + 9596208);              // 4096 u64 = 8,192 f32
    u16* wrph = (u16*)(W + 9604400);              // 589,824 u16
    u16* wrpl = (u16*)(W + 9899312);
    u16* wihh = (u16*)(W + 10194224);             // 786,432 u16
    u16* wihl = (u16*)(W + 10587440);
    u16* wrsh = (u16*)(W + 10980656);             // 393,216 u16
    u16* wrsl = (u16*)(W + 11177264);
    u16* mwh  = (u16*)(W + 11373872);             // 262,144 u16
    u16* mwl  = (u16*)(W + 11504944);
    // total ~11,636,016 f32 = 46.5 MB

    // init
    hipMemsetAsync(wr, 0, (size_t)393216 * 4, stream);
    hipMemsetAsync(ex, 0, (size_t)4096 * 8, stream);
    hipMemsetAsync(Wsph, 0, (size_t)2 * 2854912 * 2, stream);  // Wsph+Wspl contiguous

    pack_w<<<(4 * 8 * 32 * 64 * 8 + 255) / 256, 256, 0, stream>>>(Whh_f, Whh_b, pw);
    wsplit_kernel<<<dim3(17, 17, 10), dim3(32, 8), 0, stream>>>(biaffW, Wsph, Wspl);

    // xw = word_reps @ [Wih_f; Wih_b]^T + bias (MFMA hi/lo)
    split_hl<<<(589824 + 255) / 256, 256, 0, stream>>>(word_reps, wrph, wrpl, 589824);
    split_hl<<<(786432 + 255) / 256, 256, 0, stream>>>(Wih_f, wihh, wihl, 786432);
    gemm_mfma_hl<<<dim3(16, 12), 256, 0, stream>>>(wrph, wrpl, wihh, wihl, b_f, xw, 768, 2048, 0);
    split_hl<<<(786432 + 255) / 256, 256, 0, stream>>>(Wih_b, wihh, wihl, 786432);
    gemm_mfma_hl<<<dim3(16, 12), 256, 0, stream>>>(wrph, wrpl, wihh, wihl, b_b, xw + 1024, 768, 2048, 0);

    lstm_mfma<<<4, 512, 0, stream>>>(xw, pw, word_length, wr, ex);

    // HT = [gelu(wr@mlp1) | gelu(wr@mlp2) | leaky(wr@head) | leaky(wr@tail)]
    split_hl<<<(393216 + 255) / 256, 256, 0, stream>>>(wr, wrsh, wrsl, 393216);
    split_hl<<<(262144 + 255) / 256, 256, 0, stream>>>(mlp1_w, mwh, mwl, 262144);
    gemm_mfma_hl<<<dim3(8, 12), 256, 0, stream>>>(wrsh, wrsl, mwh, mwl, mlp1_b, HT, 512, 2048, 1);
    split_hl<<<(262144 + 255) / 256, 256, 0, stream>>>(mlp2_w, mwh, mwl, 262144);
    gemm_mfma_hl<<<dim3(8, 12), 256, 0, stream>>>(wrsh, wrsl, mwh, mwl, mlp2_b, HT + 512, 512, 2048, 1);
    split_hl<<<(262144 + 255) / 256, 256, 0, stream>>>(head_w, mwh, mwl, 262144);
    gemm_mfma_hl<<<dim3(8, 12), 256, 0, stream>>>(wrsh, wrsl, mwh, mwl, head_b, HT + 1024, 512, 2048, 2);
    split_hl<<<(262144 + 255) / 256, 256, 0, stream>>>(tail_w, mwh, mwl, 262144);
    gemm_mfma_hl<<<dim3(8, 12), 256, 0, stream>>>(wrsh, wrsl, mwh, mwl, tail_b, HT + 1536, 512, 2048, 2);

    split_ht<<<(768 * KP + 255) / 256, 256, 0, stream>>>(HT, h1h, h1l, t1h, t1l);
    hvtv_kernel<<<40, 192, 0, stream>>>(HT, W_co, hv, tv);
    ttab_kernel<<<2, 256, 0, stream>>>(size_emb, W_co, Tt);

    // Mb pads must be zero (and non-NaN on first call): memset both arrays.
    // Mbh aliases xw/pw/wr — all dead by this point.
    hipMemsetAsync(Mbh, 0, (size_t)4177920 * 2, stream);
    hipMemsetAsync(Mbl, 0, (size_t)4177920 * 2, stream);

    biaff_mfma<<<dim3(41, 12), 256, 0, stream>>>(h1h, h1l, Wsph, Wspl, Mbh, Mbl);
    final_mfma<<<dim3(3, 120), 256, 0, stream>>>(Mbh, Mbl, t1h, t1l, hv, tv, Tt, (float*)d_out);
}